// Round 8
// baseline (7116.254 us; speedup 1.0000x reference)
//
#include <hip/hip_runtime.h>
#include <hip/hip_bf16.h>

typedef __attribute__((ext_vector_type(8))) short short8;
typedef __attribute__((ext_vector_type(4))) float f32x4;
typedef __attribute__((ext_vector_type(16))) float f32x16;

#define LRELU_SLOPE 0.2f
#define ACT_GAIN 1.41421356237309515f
#define WG_RGB 0.04419417382415922f   // 1/sqrt(512)
#define X1(v) ((((v) >> 2) ^ ((v) >> 3)) & 1)

__device__ __forceinline__ void glds16(const short* g, short* l) {
    __builtin_amdgcn_global_load_lds(
        (const __attribute__((address_space(1))) unsigned int*)g,
        (__attribute__((address_space(3))) unsigned int*)l, 16, 0, 0);
}

// ---------------- PRE1: fused init (blk<1088) + styles (<1120) + prepw (<1632)
__global__ __launch_bounds__(256) void k_pre1(
    __hip_bfloat16* __restrict__ Ypad, const float* __restrict__ rgb_b,
    float* __restrict__ img, const float* __restrict__ wsin,
    const float* __restrict__ caw, const float* __restrict__ cab,
    const float* __restrict__ raw_, const float* __restrict__ rab,
    float* __restrict__ sbuf, float* __restrict__ s2buf,
    const float* __restrict__ conv_w, float* __restrict__ w2sum,
    __hip_bfloat16* __restrict__ Abf) {
    __shared__ float shf[4608];
    int blk = blockIdx.x, tid = threadIdx.x;
    if (blk < 1088) {
        if (blk < 1040) {                   // Ypad border: 4160 slots, 4/block
            int gslot = blk*4 + (tid >> 6);
            int b = gslot / 260;
            int cell = gslot - b*260;
            int h, w;
            if (cell < 66)       { h = 0;          w = cell; }
            else if (cell < 132) { h = 65;         w = cell - 66; }
            else if (cell < 196) { h = cell - 131; w = 0; }
            else                 { h = cell - 195; w = 65; }
            short8 z = {};
            *(short8*)((short*)Ypad + (((b*66 + h)*66) + w)*512 + (tid & 63)*8) = z;
        } else {                            // img init
            int blk2 = blk - 1040;
            #pragma unroll
            for (int j = 0; j < 4; ++j) {
                int f4 = blk2*1024 + j*256 + tid;
                int b3 = f4 >> 10;
                int o3 = b3 % 3;
                float v = rgb_b[o3];
                f32x4 vv = {v, v, v, v};
                *(f32x4*)(img + f4*4) = vv;
            }
        }
    } else if (blk < 1120) {                // styles
        int idx = blk - 1088;
        int b = idx >> 1, which = idx & 1;
        int lane = tid & 63, wv = tid >> 6;
        const float* aw = which ? raw_ : caw;
        const float* ab = which ? rab : cab;
        float scale = which ? WG_RGB : 1.0f;
        float* op = which ? s2buf : sbuf;
        float* wsv = shf;
        wsv[tid]       = wsin[(b*2 + which)*512 + tid];
        wsv[tid + 256] = wsin[(b*2 + which)*512 + tid + 256];
        __syncthreads();
        for (int c = wv; c < 512; c += 4) {
            float p = 0.f;
            #pragma unroll
            for (int kk = 0; kk < 8; ++kk)
                p += aw[c*512 + kk*64 + lane] * wsv[kk*64 + lane];
            #pragma unroll
            for (int off = 32; off; off >>= 1) p += __shfl_down(p, off, 64);
            if (lane == 0) op[b*512 + c] = (p + ab[c]) * scale;
        }
    } else {                                // prepw
        int o = blk - 1120;
        float* wrow = shf;
        const f32x4* src = (const f32x4*)(conv_w + o*4608);
        #pragma unroll
        for (int r = 0; r < 5; ++r) {
            int idx = tid + (r << 8);
            if (idx < 1152) *(f32x4*)&wrow[idx*4] = src[idx];
        }
        __syncthreads();
        #pragma unroll
        for (int j = 0; j < 2; ++j) {
            int c = tid + (j << 8);
            float sum = 0.f;
            #pragma unroll
            for (int t = 0; t < 9; ++t) {
                float v = wrow[c*9 + t];
                sum += v*v;
                Abf[(t*512 + o)*512 + c] = __float2bfloat16(v);
            }
            w2sum[o*512 + c] = sum;
        }
    }
}

// ---------------- PRE2: fused dcoef (blk<2048) + ypad (vectorized stores)
__global__ __launch_bounds__(256) void k_pre2(
    const float* __restrict__ sbuf, const float* __restrict__ w2sum,
    const float* __restrict__ s2buf, const float* __restrict__ rgb_w,
    float* __restrict__ dcoef, float* __restrict__ rgbc,
    const float* __restrict__ cst, __hip_bfloat16* __restrict__ Ypad) {
    __shared__ float tile[64][65];
    __shared__ float sv[64];
    int blk = blockIdx.x, tid = threadIdx.x;
    if (blk < 2048) {                       // dcoef + rgbc
        int gw = blk*4 + (tid >> 6);
        int lane = tid & 63;
        int b = gw >> 9, o = gw & 511;
        float acc = 0.f;
        #pragma unroll
        for (int i = 0; i < 8; ++i) {
            int c = (i << 6) + lane;
            float svv = sbuf[(b << 9) + c];
            acc += svv*svv*w2sum[(o << 9) + c];
        }
        #pragma unroll
        for (int off = 32; off; off >>= 1) acc += __shfl_down(acc, off, 64);
        if (lane == 0) dcoef[(b << 9) + o] = rsqrtf(acc + 1e-8f);
        if (blk < 96) {
            int flat = blk*256 + tid;
            int bb = flat / 1536;
            int r  = flat - bb*1536;
            int c  = r & 511;
            rgbc[flat] = rgb_w[r] * s2buf[bb*512 + c];
        }
    } else {                                // ypad interior, short8 stores
        int blk2 = blk - 2048;
        int b = blk2 >> 6, h = blk2 & 63;
        for (int cc = 0; cc < 8; ++cc) {
            int c0 = cc << 6;
            #pragma unroll
            for (int it = 0; it < 16; ++it) {
                int cl = (it << 2) + (tid >> 6);
                int w = tid & 63;
                tile[cl][w] = cst[(c0 + cl)*4096 + (h << 6) + w];
            }
            if (tid < 64) sv[tid] = sbuf[(b << 9) + c0 + tid];
            __syncthreads();
            #pragma unroll
            for (int it = 0; it < 2; ++it) {
                int u = (it << 8) + tid;        // 0..511 = 64 w x 8 cgroups
                int w = u >> 3, cg = u & 7;
                short8 v;
                #pragma unroll
                for (int j = 0; j < 8; ++j) {
                    float f = sv[cg*8 + j] * tile[cg*8 + j][w];
                    __hip_bfloat16 bf = __float2bfloat16(f);
                    v[j] = reinterpret_cast<short&>(bf);
                }
                *(short8*)((short*)Ypad + (((b*66 + h + 1)*66) + (w + 1))*512
                           + c0 + cg*8) = v;
            }
            __syncthreads();
        }
    }
}

// ---------------- main conv GEMM R8: K16 chunks x 3-tap phases (96 barriers),
// A 6-slot ring of 8KB taps (publish 3/phase, distance 1 phase, disjoint
// slots mod 6), B double-buffer 2x12.4KB (staged 2 glds/wave at dh0).
// LDS 74.5KB -> 2 blocks/CU (16 waves): cross-block pipe overlap.
// NO intra-phase fences / manual lgkmcnt — compiler schedules the phase body
// (m97-verified counted lgkmcnt; m141 showed order-pinning costs 40%).
// All swizzled frag offsets precomputed (kills per-phase VALU).
// vmcnt ledger per chunk {2,0,0}, issue order A,A,A then B,B (in-order
// retirement => vmcnt(2) retires the A's). X1 swizzle (R4-proven).
__global__ __launch_bounds__(512, 4) void conv_gemm(
    const short* __restrict__ Abf,   // [9][512][512] bf16
    const short* __restrict__ Ypad,  // [16][66][66][512] bf16
    const float* __restrict__ dcoef, // [16][512]
    const float* __restrict__ noise, // [4096]
    const float* __restrict__ nstr,  // [1]
    const float* __restrict__ bias,  // [512]
    const float* __restrict__ rgbc,  // [16][3][512]
    float* __restrict__ xout,        // [16][512][4096]
    float* __restrict__ img)         // [16][3][4096], pre-init to rgb_b
{
    __shared__ short SH[37248];       // 74496B: Aring 6x4096 + Bbuf 2x6336
    short* Aring = SH;                // [6 slot][256 row][16 c] (slot=8KB)
    short* Bbuf  = SH + 24576;        // [2 half][396 pos][2x16B halves]
    float (*red)[3][2] = (float (*)[3][2])SH;   // post-loop overlay

    int tid = threadIdx.x, lane = tid & 63, wv = tid >> 6;   // wv 0..7
    int wr = wv >> 2, wc = wv & 3;    // wave tile rows wr*128, cols wc*64
    int ml32 = lane & 31, hi = lane >> 5;

    int blk = blockIdx.x;
    int xcd = blk & 7, idx = blk >> 3;
    int v = xcd * 64 + idx;           // bijective: 512 blocks, 64 per XCD
    int mblk = v & 1, nblk = v >> 1;  // nblk 0..255
    int b = nblk >> 4;
    int hw0 = (nblk & 15) << 8;       // 256 hw per block
    int h0 = hw0 >> 6;                // top padded row of 6-row halo window
    int o0 = mblk << 8;

    // ---- A staging source (per thread, one 16B unit per tap-slot round)
    int agofs;
    {
        int row = tid >> 1, half = tid & 1;
        agofs = ((o0 + row) << 9) + (half ^ X1(row))*8;
    }
    // ---- B staging sources: 792 units (396 pos x 2 halves), wave stripe 99
    int bsrc1, bsrc2;
    {
        int j = wv*99 + lane;                 // call 1: all 64 lanes
        int pos = j >> 1, half = j & 1;
        int q = half ^ X1(pos);
        int hl = pos / 66, ww = pos - hl*66;
        bsrc1 = (((b*66 + h0 + hl)*66) + ww)*512 + q*8;
        int l2 = lane < 35 ? lane : 34;       // call 2: lanes 0..34
        int j2 = wv*99 + 64 + l2;
        int pos2 = j2 >> 1, half2 = j2 & 1;
        int q2 = half2 ^ X1(pos2);
        int hl2 = pos2 / 66, ww2 = pos2 - hl2*66;
        bsrc2 = (((b*66 + h0 + hl2)*66) + ww2)*512 + q2*8;
    }
    // ---- frag read offsets (precomputed, swizzle folded in)
    int aro[4];
    #pragma unroll
    for (int mi = 0; mi < 4; ++mi) {
        int row = wr*128 + mi*32 + ml32;
        aro[mi] = row*16 + ((hi ^ X1(row)) << 3);
    }
    int pb0 = wc*66 + ml32;
    int boff[9][2];
    #pragma unroll
    for (int t = 0; t < 9; ++t)
        #pragma unroll
        for (int ni = 0; ni < 2; ++ni) {
            int p_ = pb0 + (t/3)*66 + (t%3) + ni*32;
            boff[t][ni] = p_*16 + ((hi ^ X1(p_)) << 3);
        }

    short* AW = Aring + wv*512;       // wave-uniform A write base (+slot*4096)
    short* B0w = Bbuf + wv*792;       // wave-uniform B write base, half0
    short* B1w = Bbuf + 6336 + wv*792;

    f32x16 acc[4][2] = {};
    short8 fa0[4], fa1[4], fa2[4], fb0[2], fb1[2], fb2[2];

    // ---- prologue: A taps 0,1,2 -> slots 0,1,2 (c0=0); B chunk0 -> half0
    glds16(Abf + (0 << 18) + agofs, AW);
    glds16(Abf + (1 << 18) + agofs, AW + 4096);
    glds16(Abf + (2 << 18) + agofs, AW + 8192);
    glds16(Ypad + bsrc1, B0w);
    if (lane < 35) glds16(Ypad + bsrc2, B0w + 512);
    asm volatile("s_waitcnt vmcnt(0)" ::: "memory");
    __builtin_amdgcn_s_barrier();
    asm volatile("" ::: "memory");

#define MM(FA, FB)                                                          \
    _Pragma("unroll")                                                       \
    for (int mi = 0; mi < 4; ++mi)                                          \
        _Pragma("unroll")                                                   \
        for (int ni = 0; ni < 2; ++ni)                                      \
            acc[mi][ni] = __builtin_amdgcn_mfma_f32_32x32x16_bf16(          \
                FA[mi], FB[ni], acc[mi][ni], 0, 0, 0);

#define PUB(G0, DH, K, C0V, CNV)                                            \
    { constexpr int tp = 3*(DH) + 3 + (K);                                  \
      constexpr int sl = ((G0) + tp) % 6;                                   \
      constexpr int te = tp % 9;                                            \
      glds16(Abf + (te << 18) + ((tp <= 8) ? (C0V) : (CNV)) + agofs,        \
             AW + sl*4096); }

#define RDT(G0, DH, TL, FA, FB, BHR)                                        \
    { constexpr int sl = ((G0) + 3*(DH) + (TL)) % 6;                        \
      constexpr int t = 3*(DH) + (TL);                                      \
      _Pragma("unroll")                                                     \
      for (int mi = 0; mi < 4; ++mi)                                        \
          FA[mi] = *(const short8*)(Aring + sl*4096 + aro[mi]);             \
      _Pragma("unroll")                                                     \
      for (int ni = 0; ni < 2; ++ni)                                        \
          FB[ni] = *(const short8*)((BHR) + boff[t][ni]); }

#define PH(G0, DH, C0V, CNV, BHR, BSW, CB)                                  \
    {                                                                       \
        PUB(G0, DH, 0, C0V, CNV)                                            \
        PUB(G0, DH, 1, C0V, CNV)                                            \
        PUB(G0, DH, 2, C0V, CNV)                                            \
        if ((DH) == 0) {                                                    \
            glds16(Ypad + bsrc1 + (CB), BSW);                               \
            if (lane < 35) glds16(Ypad + bsrc2 + (CB), (BSW) + 512);        \
        }                                                                   \
        RDT(G0, DH, 0, fa0, fb0, BHR)                                       \
        RDT(G0, DH, 1, fa1, fb1, BHR)                                       \
        __builtin_amdgcn_s_setprio(1);                                      \
        MM(fa0, fb0)                                                        \
        RDT(G0, DH, 2, fa2, fb2, BHR)                                       \
        MM(fa1, fb1)                                                        \
        MM(fa2, fb2)                                                        \
        __builtin_amdgcn_s_setprio(0);                                      \
        asm volatile("s_waitcnt vmcnt(%0)" :: "i"((DH) == 0 ? 2 : 0)        \
                     : "memory");                                           \
        __builtin_amdgcn_s_barrier();                                       \
        asm volatile("" ::: "memory");                                      \
    }

    for (int cc = 0; cc < 16; ++cc) {
        int c0e = cc << 5;                 // even chunk c=2cc (half0, G0=0)
        int c0o = c0e + 16;                // odd chunk c=2cc+1 (half1, G0=3)
        int c0n2 = (c0e + 32) & 511;       // chunk 2cc+2 (wraps: dummy-safe)
        PH(0, 0, c0e, c0o, Bbuf, B1w, c0o)
        PH(0, 1, c0e, c0o, Bbuf, B1w, c0o)
        PH(0, 2, c0e, c0o, Bbuf, B1w, c0o)
        PH(3, 0, c0o, c0n2, Bbuf + 6336, B0w, c0n2)
        PH(3, 1, c0o, c0n2, Bbuf + 6336, B0w, c0n2)
        PH(3, 2, c0o, c0n2, Bbuf + 6336, B0w, c0n2)
    }
#undef PH
#undef RDT
#undef PUB
#undef MM

    // ---------------- epilogue: demod + noise + bias + lrelu + store + ToRGB
    // C/D layout (32x32): col = lane&31, row = (r&3) + 8*(r>>2) + 4*hi
    float ns = nstr[0];
    float pr0[2] = {0.f, 0.f}, pr1[2] = {0.f, 0.f}, pr2[2] = {0.f, 0.f};
    #pragma unroll
    for (int mi = 0; mi < 4; ++mi) {
        int ob = o0 + wr*128 + mi*32 + hi*4;
        f32x4 dc[4], bs[4], c0r[4], c1r[4], c2r[4];
        #pragma unroll
        for (int g = 0; g < 4; ++g) {
            dc[g]  = *(const f32x4*)(dcoef + (b << 9) + ob + g*8);
            bs[g]  = *(const f32x4*)(bias + ob + g*8);
            c0r[g] = *(const f32x4*)(rgbc + b*1536 + ob + g*8);
            c1r[g] = *(const f32x4*)(rgbc + b*1536 + 512 + ob + g*8);
            c2r[g] = *(const f32x4*)(rgbc + b*1536 + 1024 + ob + g*8);
        }
        #pragma unroll
        for (int ni = 0; ni < 2; ++ni) {
            int nl = wc*64 + ni*32 + ml32;
            int hw = hw0 + nl;
            float nz = noise[hw] * ns;
            #pragma unroll
            for (int g = 0; g < 4; ++g)
                #pragma unroll
                for (int t = 0; t < 4; ++t) {
                    float vv = acc[mi][ni][g*4 + t] * dc[g][t] + nz + bs[g][t];
                    vv = (vv < 0.f ? LRELU_SLOPE*vv : vv) * ACT_GAIN;
                    xout[(((b << 9) + ob + g*8 + t) << 12) + hw] = vv;
                    pr0[ni] += vv * c0r[g][t];
                    pr1[ni] += vv * c1r[g][t];
                    pr2[ni] += vv * c2r[g][t];
                }
        }
    }
    #pragma unroll
    for (int ni = 0; ni < 2; ++ni) {
        pr0[ni] += __shfl_down(pr0[ni], 32, 64);
        pr1[ni] += __shfl_down(pr1[ni], 32, 64);
        pr2[ni] += __shfl_down(pr2[ni], 32, 64);
    }
    if (lane < 32) {
        #pragma unroll
        for (int ni = 0; ni < 2; ++ni) {
            int nl = wc*64 + ni*32 + ml32;
            red[nl][0][wr] = pr0[ni];
            red[nl][1][wr] = pr1[ni];
            red[nl][2][wr] = pr2[ni];
        }
    }
    __syncthreads();
    for (int p = tid; p < 768; p += 512) {
        int o3 = p >> 8, nl = p & 255;
        atomicAdd(img + ((b*3 + o3) << 12) + hw0 + nl, red[nl][o3][0] + red[nl][o3][1]);
    }
}

extern "C" void kernel_launch(void* const* d_in, const int* in_sizes, int n_in,
                              void* d_out, int out_size, void* d_ws, size_t ws_size,
                              hipStream_t stream) {
    (void)in_sizes; (void)n_in; (void)out_size; (void)ws_size;
    const float* wsin   = (const float*)d_in[0];   // [16][2][512]
    const float* cst    = (const float*)d_in[1];   // [512][64][64]
    const float* conv_w = (const float*)d_in[2];   // [512][512][3][3]
    const float* conv_b = (const float*)d_in[3];   // [512]
    const float* caw    = (const float*)d_in[4];   // [512][512]
    const float* cab    = (const float*)d_in[5];   // [512]
    const float* noise  = (const float*)d_in[6];   // [64][64]
    const float* nstr   = (const float*)d_in[7];   // [1]
    const float* rgb_w  = (const float*)d_in[8];   // [3][512][1][1]
    const float* rgb_b  = (const float*)d_in[9];   // [3]
    const float* raw_   = (const float*)d_in[10];  // [512][512]
    const float* rab    = (const float*)d_in[11];  // [512]

    char* wsb = (char*)d_ws;
    float* sbuf   = (float*)(wsb + 0);         // 16*512 f32
    float* s2buf  = (float*)(wsb + 32768);     // 16*512 f32
    float* dcoef  = (float*)(wsb + 65536);     // 16*512 f32
    float* rgbc   = (float*)(wsb + 98304);     // 16*3*512 f32
    float* w2sum  = (float*)(wsb + 196608);    // 512*512 f32 ([o][c])
    __hip_bfloat16* Abf  = (__hip_bfloat16*)(wsb + 1245184);  // 9*512*512 bf16
    __hip_bfloat16* Ypad = (__hip_bfloat16*)(wsb + 5963776);  // 16*66*66*512 bf16

    float* xout = (float*)d_out;               // [16][512][4096]
    float* img  = xout + 33554432;             // [16][3][4096]

    k_pre1<<<1632, 256, 0, stream>>>(Ypad, rgb_b, img, wsin, caw, cab, raw_, rab,
                                     sbuf, s2buf, conv_w, w2sum, Abf);
    k_pre2<<<3072, 256, 0, stream>>>(sbuf, w2sum, s2buf, rgb_w, dcoef, rgbc,
                                     cst, Ypad);
    conv_gemm<<<512, 512, 0, stream>>>((const short*)Abf, (const short*)Ypad,
                                       dcoef, noise, nstr, conv_b, rgbc, xout, img);
}